// Round 10
// baseline (580.070 us; speedup 1.0000x reference)
//
#include <hip/hip_runtime.h>
#include <hip/hip_fp16.h>
#include <math.h>

// ---------------------------------------------------------------------------
// GCN: 2-kernel bucket CSR build (over-provisioned regions, no scans)
//      + wave-per-node fp16 gather aggregation + split-bf16 MFMA GEMMs.
//   bucket = col>>6 (64 nodes). CAP=4096 >> mean 2048 (sigma 45) -> regions
//   cannot overflow. Global atomic cursors live on 2048 padded 64B lines
//   (L2-resident) -- unlike 100k random-line histograms (R2/R5: 200MB WRITE).
//   xws = (X @ W) * dinv[node] stored fp16; x1/x2 fp16 (exact hi/lo split).
//   x_out[n] = relu(dinv[n]*(xws[n] + sum_{e in CSR[n]} xws[srow[e]]) + b)
//   out = sigmoid(relu([x,x1,x2]@Wl1 + bl1) @ Wl2 + bl2)   (fused head)
// ---------------------------------------------------------------------------

typedef __attribute__((ext_vector_type(8))) short bf16x8;
typedef __attribute__((ext_vector_type(4))) float f32x4;

#define BSHIFT 6                 // 64 cols per bucket
#define CAP 4096                 // region capacity (edges); mean fill 50%

// ---------------- bucket scatter (global padded cursors) ----------------
__global__ void k_bscatter(const int* __restrict__ row, const int* __restrict__ col,
                           int* __restrict__ qcur, int* __restrict__ bpack, int e) {
    int i = blockIdx.x * blockDim.x + threadIdx.x;
    if (i >= e) return;
    int c = col[i];
    int b = c >> BSHIFT;
    int pos = atomicAdd(&qcur[b * 16], 1);
    bpack[(size_t)b * CAP + pos] = (row[i] << BSHIFT) | (c & 63);
}

// per-bucket: region-local node lists (srow), offs2 int2 {start,end}, dinv
__global__ __launch_bounds__(256) void k_bfill(
    const int* __restrict__ bpack, const int* __restrict__ qcur,
    int2* __restrict__ offs2, int* __restrict__ srow,
    float* __restrict__ dinv, int n) {
    __shared__ int h[64];
    __shared__ int cur[64];
    int b = blockIdx.x, tid = threadIdx.x;
    int nodeb = b << BSHIFT;
    int cnt = qcur[b * 16];
    int s0 = b * CAP;
    if (tid < 64) h[tid] = 0;
    __syncthreads();
    for (int i = tid; i < cnt; i += 256) atomicAdd(&h[bpack[s0 + i] & 63], 1);
    __syncthreads();
    if (tid < 64) {                      // threads 0-63 = wave 0
        int v = h[tid];
        int s = v;
        for (int d = 1; d < 64; d <<= 1) {
            int t = __shfl_up(s, d);
            if (tid >= d) s += t;
        }
        int local = s - v;               // exclusive scan
        cur[tid] = s0 + local;
        int node = nodeb + tid;
        if (node < n) {
            offs2[node] = make_int2(s0 + local, s0 + local + v);
            dinv[node] = rsqrtf((float)v + 1.0f);
        }
    }
    __syncthreads();
    for (int i = tid; i < cnt; i += 256) {
        int p = bpack[s0 + i];
        int pos = atomicAdd(&cur[p & 63], 1);
        srow[pos] = p >> BSHIFT;
    }
}

// ---------------- weight prep: frag-ordered bf16 hi/lo ----------------
__global__ void k_prep_w(const float* __restrict__ W1, const float* __restrict__ W2,
                         const float* __restrict__ Wl1, short* __restrict__ wb) {
    int i = blockIdx.x * blockDim.x + threadIdx.x;
    if (i >= 5 * 16384) return;
    int blk = i >> 14, rem = i & 16383;
    int k = rem >> 7, n = rem & 127;
    float v;
    if (blk == 0) v = W1[rem];
    else if (blk == 1) v = W2[rem];
    else v = Wl1[((blk - 2) * 128 + k) * 128 + n];
    unsigned u = __float_as_uint(v);
    unsigned hb = u & 0xFFFF0000u;
    float lo = v - __uint_as_float(hb);
    unsigned lb = __float_as_uint(lo);
    int kk = k >> 5, km = k & 31;
    int half = km >> 4, kq = km & 15, g = kq >> 2, j = kq & 3;
    int nt = n >> 4, c = n & 15;
    size_t idx = ((size_t)(kk * 8 + nt) * 64 + (g * 16 + c)) * 8 + (half * 4 + j);
    size_t base = (size_t)blk * 32768;
    wb[base + idx] = (short)(hb >> 16);
    wb[base + 16384 + idx] = (short)(lb >> 16);
}

__device__ inline short2 split_f(float x) {
    unsigned u = __float_as_uint(x);
    unsigned hb = u & 0xFFFF0000u;
    short h = (short)(u >> 16);
    short l = (short)(__float_as_uint(x - __uint_as_float(hb)) >> 16);
    return make_short2(h, l);
}

// load 8 A-channels {off..off+3, off+16..off+19} as floats (fp32 or fp16 src)
__device__ inline void loadA8(const void* src, int f16, size_t node, int off,
                              float* v) {
    if (f16) {
        const __half* p = (const __half*)src + node * 128 + off;
        int2 a = *(const int2*)p;            // 4 halves
        int2 b = *(const int2*)(p + 16);     // 4 halves
        const __half2* ah = (const __half2*)&a;
        const __half2* bh = (const __half2*)&b;
        float2 f;
        f = __half22float2(ah[0]); v[0] = f.x; v[1] = f.y;
        f = __half22float2(ah[1]); v[2] = f.x; v[3] = f.y;
        f = __half22float2(bh[0]); v[4] = f.x; v[5] = f.y;
        f = __half22float2(bh[1]); v[6] = f.x; v[7] = f.y;
    } else {
        const float* p = (const float*)src + node * 128 + off;
        float4 v0 = *(const float4*)p;
        float4 v1 = *(const float4*)(p + 16);
        v[0] = v0.x; v[1] = v0.y; v[2] = v0.z; v[3] = v0.w;
        v[4] = v1.x; v[5] = v1.y; v[6] = v1.z; v[7] = v1.w;
    }
}

// ---------------- MFMA GEMM ----------------
// mode 0: Yh[node][ch] = fp16((src0 @ Wblk) * dscale[node])      (nkb=1)
// mode 1: out[node] = sigmoid(relu(sum_kb srcKB@Wblk + bl1).wl2 + bl2) (nkb=3)
// f16mask bit kb: srcKB is fp16
__global__ __launch_bounds__(256) void k_gemm_mfma(
    const void* __restrict__ src0, const void* __restrict__ src1,
    const void* __restrict__ src2, const short* __restrict__ wb,
    const float* __restrict__ dscale, const float* __restrict__ bias,
    const float* __restrict__ wl2, const float* __restrict__ bl2,
    void* __restrict__ Y, int n, int nkb, int mode, int f16mask) {
    __shared__ short wl[32768];          // 64 KB: [hi 16384][lo 16384]
    int tid = threadIdx.x;
    int wave = tid >> 6, lane = tid & 63;
    int g = lane >> 4, c = lane & 15;
    int base = blockIdx.x * 128 + wave * 32;

    f32x4 acc[2][8];
#pragma unroll
    for (int a = 0; a < 2; ++a)
#pragma unroll
        for (int b = 0; b < 8; ++b) acc[a][b] = (f32x4){0.f, 0.f, 0.f, 0.f};

    for (int kb = 0; kb < nkb; ++kb) {
        const void* src = (kb == 0) ? src0 : ((kb == 1) ? src1 : src2);
        int f16 = (f16mask >> kb) & 1;
        __syncthreads();
        {
            const int4* s = (const int4*)(wb + (size_t)kb * 32768);
            int4* d = (int4*)wl;
            for (int it = tid; it < 4096; it += 256) d[it] = s[it];
        }
        __syncthreads();
#pragma unroll
        for (int kk = 0; kk < 4; ++kk) {
            bf16x8 ah[2], al[2];
#pragma unroll
            for (int mf = 0; mf < 2; ++mf) {
                int node = base + mf * 16 + c;
                if (node >= n) node = n - 1;     // clamp; stores are guarded
                float v[8];
                loadA8(src, f16, (size_t)node, kk * 32 + g * 4, v);
                short2 s;
#pragma unroll
                for (int q = 0; q < 8; ++q) {
                    s = split_f(v[q]);
                    ah[mf][q] = s.x;
                    al[mf][q] = s.y;
                }
            }
#pragma unroll
            for (int nt = 0; nt < 8; ++nt) {
                int bidx = ((kk * 8 + nt) * 64 + lane) * 8;
                bf16x8 bh = *(const bf16x8*)&wl[bidx];
                bf16x8 bl = *(const bf16x8*)&wl[16384 + bidx];
#pragma unroll
                for (int mf = 0; mf < 2; ++mf) {
                    acc[mf][nt] = __builtin_amdgcn_mfma_f32_16x16x32_bf16(ah[mf], bh, acc[mf][nt], 0, 0, 0);
                    acc[mf][nt] = __builtin_amdgcn_mfma_f32_16x16x32_bf16(ah[mf], bl, acc[mf][nt], 0, 0, 0);
                    acc[mf][nt] = __builtin_amdgcn_mfma_f32_16x16x32_bf16(al[mf], bh, acc[mf][nt], 0, 0, 0);
                }
            }
        }
    }

    if (mode == 0) {
        __half* Yh = (__half*)Y;
#pragma unroll
        for (int mf = 0; mf < 2; ++mf) {
#pragma unroll
            for (int j = 0; j < 4; ++j) {
                int node = base + mf * 16 + g * 4 + j;   // row=(lane>>4)*4+reg
                if (node >= n) continue;
                float s = dscale[node];
#pragma unroll
                for (int nt = 0; nt < 8; ++nt)
                    Yh[(size_t)node * 128 + nt * 16 + c] =
                        __float2half(acc[mf][nt][j] * s);
            }
        }
    } else {
        float* Yf = (float*)Y;
        float wv[8], bv[8];
#pragma unroll
        for (int nt = 0; nt < 8; ++nt) {
            wv[nt] = wl2[nt * 16 + c];
            bv[nt] = bias[nt * 16 + c];
        }
        float blv = bl2[0];
#pragma unroll
        for (int mf = 0; mf < 2; ++mf) {
#pragma unroll
            for (int j = 0; j < 4; ++j) {
                float partial = 0.f;
#pragma unroll
                for (int nt = 0; nt < 8; ++nt)
                    partial += fmaxf(acc[mf][nt][j] + bv[nt], 0.f) * wv[nt];
#pragma unroll
                for (int m = 1; m < 16; m <<= 1) partial += __shfl_xor(partial, m);
                int node = base + mf * 16 + g * 4 + j;
                if (c == 0 && node < n)
                    Yf[node] = 1.f / (1.f + expf(-(partial + blv)));
            }
        }
    }
}

// ---------------- aggregation (wave-per-node fp16 gather, 16-deep) ---------
__global__ __launch_bounds__(256) void k_aggregate(
    const __half* __restrict__ xws, const float* __restrict__ dinv,
    const float* __restrict__ bias, const int2* __restrict__ offs2,
    const int* __restrict__ srow, __half* __restrict__ out, int n) {
    long long t = (long long)blockIdx.x * blockDim.x + threadIdx.x;
    int node = (int)(t >> 6);
    int l = (int)t & 63;
    if (node >= n) return;
    int2 se = offs2[node];
    int start = se.x, end = se.y;
    const __half* xb = xws + l * 2;      // lane's half2 within a row
    float2 acc = __half22float2(*(const __half2*)(xb + (size_t)node * 128));
    int e = start;
    for (; e + 15 < end; e += 16) {
        int r[16];
#pragma unroll
        for (int q = 0; q < 16; ++q)
            r[q] = __builtin_nontemporal_load(&srow[e + q]);
        float2 v[16];
#pragma unroll
        for (int q = 0; q < 16; ++q)
            v[q] = __half22float2(*(const __half2*)(xb + (size_t)r[q] * 128));
        float sx = 0.f, sy = 0.f;
#pragma unroll
        for (int q = 0; q < 16; ++q) { sx += v[q].x; sy += v[q].y; }
        acc.x += sx;
        acc.y += sy;
    }
    for (; e + 7 < end; e += 8) {
        int r[8];
#pragma unroll
        for (int q = 0; q < 8; ++q)
            r[q] = __builtin_nontemporal_load(&srow[e + q]);
        float2 v[8];
#pragma unroll
        for (int q = 0; q < 8; ++q)
            v[q] = __half22float2(*(const __half2*)(xb + (size_t)r[q] * 128));
        float sx = 0.f, sy = 0.f;
#pragma unroll
        for (int q = 0; q < 8; ++q) { sx += v[q].x; sy += v[q].y; }
        acc.x += sx;
        acc.y += sy;
    }
    for (; e < end; ++e) {
        float2 v = __half22float2(*(const __half2*)(xb + (size_t)srow[e] * 128));
        acc.x += v.x;
        acc.y += v.y;
    }
    float s = dinv[node];
    float2 b = *(const float2*)(bias + l * 2);
    acc.x = fmaxf(fmaf(acc.x, s, b.x), 0.f);
    acc.y = fmaxf(fmaf(acc.y, s, b.y), 0.f);
    __half2 hv = __float22half2_rn(acc);
    unsigned u;
    __builtin_memcpy(&u, &hv, 4);
    __builtin_nontemporal_store(u, (unsigned*)(out + (size_t)node * 128 + l * 2));
}

extern "C" void kernel_launch(void* const* d_in, const int* in_sizes, int n_in,
                              void* d_out, int out_size, void* d_ws, size_t ws_size,
                              hipStream_t stream) {
    const float* x   = (const float*)d_in[0];
    const int*   ei  = (const int*)d_in[1];
    const float* W1  = (const float*)d_in[2];
    const float* b1  = (const float*)d_in[3];
    const float* W2  = (const float*)d_in[4];
    const float* b2  = (const float*)d_in[5];
    const float* Wl1 = (const float*)d_in[6];
    const float* bl1 = (const float*)d_in[7];
    const float* Wl2 = (const float*)d_in[8];
    const float* bl2 = (const float*)d_in[9];
    float* out = (float*)d_out;

    const int N = in_sizes[0] / 128;
    const int E = in_sizes[1] / 2;
    const int* row = ei;
    const int* col = ei + E;
    const int nbuk = (N + 63) >> 6;

    char* ws = (char*)d_ws;
    size_t off = 0;
    auto alloc = [&](size_t bytes) {
        void* p = ws + off;
        off += (bytes + 255) & ~(size_t)255;
        return p;
    };
    float*  dinv  = (float*)alloc((size_t)N * 4);
    int*    qcur  = (int*)alloc((size_t)nbuk * 16 * 4);
    int2*   offs2 = (int2*)alloc((size_t)N * 8);
    int*    bpack = (int*)alloc((size_t)nbuk * CAP * 4);
    int*    srow  = (int*)alloc((size_t)nbuk * CAP * 4);
    short*  wb    = (short*)alloc((size_t)5 * 32768 * 2);
    __half* bufA  = (__half*)alloc((size_t)N * 128 * 2);  // xws (fp16)
    __half* bufB  = (__half*)alloc((size_t)N * 128 * 2);  // x1 (fp16)
    __half* bufC  = (__half*)alloc((size_t)N * 128 * 2);  // x2 (fp16)

    const int B = 256;
    int gG = (N + 127) / 128;                       // MFMA gemm tiles
    int gP = (5 * 16384 + B - 1) / B;
    int gE = (E + B - 1) / B;
    int gA = (int)(((long long)N * 64 + B - 1) / B);

    // ---- 2-kernel bucket CSR build + weight prep ----
    hipMemsetAsync(qcur, 0, (size_t)nbuk * 16 * 4, stream);
    k_prep_w<<<gP, B, 0, stream>>>(W1, W2, Wl1, wb);
    k_bscatter<<<gE, B, 0, stream>>>(row, col, qcur, bpack, E);
    k_bfill<<<nbuk, B, 0, stream>>>(bpack, qcur, offs2, srow, dinv, N);

    // ---- layer 1 ----
    k_gemm_mfma<<<gG, B, 0, stream>>>(x, nullptr, nullptr, wb,
                                      dinv, nullptr, nullptr, nullptr,
                                      bufA, N, 1, 0, 0);
    k_aggregate<<<gA, B, 0, stream>>>(bufA, dinv, b1, offs2, srow, bufB, N);

    // ---- layer 2 ----
    k_gemm_mfma<<<gG, B, 0, stream>>>(bufB, nullptr, nullptr, wb + 32768,
                                      dinv, nullptr, nullptr, nullptr,
                                      bufA, N, 1, 0, 1);
    k_aggregate<<<gA, B, 0, stream>>>(bufA, dinv, b2, offs2, srow, bufC, N);

    // ---- fused MLP head ----
    k_gemm_mfma<<<gG, B, 0, stream>>>(x, bufB, bufC, wb + 2 * 32768,
                                      nullptr, bl1, Wl2, bl2,
                                      out, N, 3, 1, 6);
}

// Round 11
// 547.738 us; speedup vs baseline: 1.0590x; 1.0590x over previous
//
#include <hip/hip_runtime.h>
#include <hip/hip_fp16.h>
#include <math.h>

// ---------------------------------------------------------------------------
// GCN: atomic-free bucket CSR build (R9 structure: LDS-privatized histogram,
// scanned per-block partials -> private contiguous scatter runs) +
// wave-per-node fp16 gather aggregation in TWO serialized half-row passes
// (halves L2 working set: 256B row = 4 lines; half-pass touches 2) +
// split-bf16 MFMA GEMMs (fp32-accurate weights; fp16 activations).
// ---------------------------------------------------------------------------

typedef __attribute__((ext_vector_type(8))) short bf16x8;
typedef __attribute__((ext_vector_type(4))) float f32x4;

#define BSHIFT 6                 // 64 cols per bucket
#define NB 256                   // histogram / scatter blocks
#define MAXBUK 2048              // >= ceil(N/64); 8 KB LDS

// ---------------- bucket histogram (LDS-privatized) ----------------
__global__ __launch_bounds__(1024) void k_bhist(const int* __restrict__ col,
                                                int* __restrict__ partials,
                                                int nbuk, int e) {
    __shared__ int h[MAXBUK];
    int tid = threadIdx.x;
    for (int i = tid; i < nbuk; i += 1024) h[i] = 0;
    __syncthreads();
    for (long long i = (long long)blockIdx.x * 1024 + tid; i < e;
         i += (long long)NB * 1024)
        atomicAdd(&h[col[i] >> BSHIFT], 1);
    __syncthreads();
    for (int i = tid; i < nbuk; i += 1024)
        partials[(size_t)blockIdx.x * nbuk + i] = h[i];
}

// wave per bucket: exclusive-scan the NB block partials (4 chunks of 64)
__global__ __launch_bounds__(256) void k_bscan(int* __restrict__ partials,
                                               int* __restrict__ tot, int nbuk) {
    int gid = blockIdx.x * 256 + threadIdx.x;
    int w = gid >> 6, l = gid & 63;
    if (w >= nbuk) return;
    int carry = 0;
#pragma unroll
    for (int c = 0; c < NB / 64; ++c) {
        size_t idx = (size_t)(c * 64 + l) * nbuk + w;
        int v = partials[idx];
        int s = v;
        for (int d = 1; d < 64; d <<= 1) {
            int t = __shfl_up(s, d);
            if (l >= d) s += t;
        }
        partials[idx] = s - v + carry;   // exclusive within bucket
        carry += __shfl(s, 63);
    }
    if (l == 0) tot[w] = carry;
}

// single-block exclusive scan of bucket totals -> base
__global__ __launch_bounds__(256) void k_btot(const int* __restrict__ tot,
                                              int* __restrict__ base,
                                              int nbuk, int e) {
    __shared__ int s[256];
    __shared__ int carry_s;
    int t = threadIdx.x;
    if (t == 0) carry_s = 0;
    __syncthreads();
    for (int bb = 0; bb < nbuk; bb += 256) {
        int v = (bb + t < nbuk) ? tot[bb + t] : 0;
        s[t] = v;
        __syncthreads();
        for (int d = 1; d < 256; d <<= 1) {
            int a = (t >= d) ? s[t - d] : 0;
            __syncthreads();
            s[t] += a;
            __syncthreads();
        }
        int c0 = carry_s;
        if (bb + t < nbuk) base[bb + t] = s[t] - v + c0;
        __syncthreads();
        if (t == 0) carry_s = c0 + s[255];
        __syncthreads();
    }
    if (t == 0) base[nbuk] = e;
}

// scatter packed (row<<6 | col&63) with per-block LDS cursors
__global__ __launch_bounds__(1024) void k_bscatter(
    const int* __restrict__ row, const int* __restrict__ col,
    const int* __restrict__ base, const int* __restrict__ partials,
    int* __restrict__ bpack, int nbuk, int e) {
    __shared__ int cur[MAXBUK];
    int tid = threadIdx.x;
    for (int i = tid; i < nbuk; i += 1024)
        cur[i] = base[i] + partials[(size_t)blockIdx.x * nbuk + i];
    __syncthreads();
    for (long long i = (long long)blockIdx.x * 1024 + tid; i < e;
         i += (long long)NB * 1024) {
        int c = col[i];
        int pos = atomicAdd(&cur[c >> BSHIFT], 1);
        bpack[pos] = (row[i] << BSHIFT) | (c & 63);
    }
}

// per-bucket: node CSR (offs, srow) + dinv, all via LDS cursors (L2-local)
__global__ __launch_bounds__(256) void k_bfill(
    const int* __restrict__ bpack, const int* __restrict__ base,
    int* __restrict__ offs, int* __restrict__ srow,
    float* __restrict__ dinv, int n, int e, int nbuk) {
    __shared__ int h[64];
    __shared__ int cur[64];
    int b = blockIdx.x, tid = threadIdx.x;
    int nodeb = b << BSHIFT;
    if (tid < 64) h[tid] = 0;
    __syncthreads();
    int s0 = base[b], s1 = base[b + 1];
    for (int i = s0 + tid; i < s1; i += 256) atomicAdd(&h[bpack[i] & 63], 1);
    __syncthreads();
    if (tid < 64) {                      // threads 0-63 = wave 0
        int v = h[tid];
        int s = v;
        for (int d = 1; d < 64; d <<= 1) {
            int t = __shfl_up(s, d);
            if (tid >= d) s += t;
        }
        int myoff = s0 + s - v;          // exclusive scan + bucket base
        cur[tid] = myoff;
        int node = nodeb + tid;
        if (node < n) {
            offs[node] = myoff;
            dinv[node] = rsqrtf((float)v + 1.0f);
        }
    }
    if (b == nbuk - 1 && tid == 0) offs[n] = e;
    __syncthreads();
    for (int i = s0 + tid; i < s1; i += 256) {
        int p = bpack[i];
        int pos = atomicAdd(&cur[p & 63], 1);
        srow[pos] = p >> BSHIFT;
    }
}

// ---------------- weight prep: frag-ordered bf16 hi/lo ----------------
__global__ void k_prep_w(const float* __restrict__ W1, const float* __restrict__ W2,
                         const float* __restrict__ Wl1, short* __restrict__ wb) {
    int i = blockIdx.x * blockDim.x + threadIdx.x;
    if (i >= 5 * 16384) return;
    int blk = i >> 14, rem = i & 16383;
    int k = rem >> 7, n = rem & 127;
    float v;
    if (blk == 0) v = W1[rem];
    else if (blk == 1) v = W2[rem];
    else v = Wl1[((blk - 2) * 128 + k) * 128 + n];
    unsigned u = __float_as_uint(v);
    unsigned hb = u & 0xFFFF0000u;
    float lo = v - __uint_as_float(hb);
    unsigned lb = __float_as_uint(lo);
    int kk = k >> 5, km = k & 31;
    int half = km >> 4, kq = km & 15, g = kq >> 2, j = kq & 3;
    int nt = n >> 4, c = n & 15;
    size_t idx = ((size_t)(kk * 8 + nt) * 64 + (g * 16 + c)) * 8 + (half * 4 + j);
    size_t base = (size_t)blk * 32768;
    wb[base + idx] = (short)(hb >> 16);
    wb[base + 16384 + idx] = (short)(lb >> 16);
}

__device__ inline short2 split_f(float x) {
    unsigned u = __float_as_uint(x);
    unsigned hb = u & 0xFFFF0000u;
    short h = (short)(u >> 16);
    short l = (short)(__float_as_uint(x - __uint_as_float(hb)) >> 16);
    return make_short2(h, l);
}

// load 8 A-channels {off..off+3, off+16..off+19} as floats (fp32 or fp16 src)
__device__ inline void loadA8(const void* src, int f16, size_t node, int off,
                              float* v) {
    if (f16) {
        const __half* p = (const __half*)src + node * 128 + off;
        int2 a = *(const int2*)p;            // 4 halves
        int2 b = *(const int2*)(p + 16);     // 4 halves
        const __half2* ah = (const __half2*)&a;
        const __half2* bh = (const __half2*)&b;
        float2 f;
        f = __half22float2(ah[0]); v[0] = f.x; v[1] = f.y;
        f = __half22float2(ah[1]); v[2] = f.x; v[3] = f.y;
        f = __half22float2(bh[0]); v[4] = f.x; v[5] = f.y;
        f = __half22float2(bh[1]); v[6] = f.x; v[7] = f.y;
    } else {
        const float* p = (const float*)src + node * 128 + off;
        float4 v0 = *(const float4*)p;
        float4 v1 = *(const float4*)(p + 16);
        v[0] = v0.x; v[1] = v0.y; v[2] = v0.z; v[3] = v0.w;
        v[4] = v1.x; v[5] = v1.y; v[6] = v1.z; v[7] = v1.w;
    }
}

// ---------------- MFMA GEMM ----------------
// mode 0: Yh[node][ch] = fp16((src0 @ Wblk) * dscale[node])      (nkb=1)
// mode 1: out[node] = sigmoid(relu(sum_kb srcKB@Wblk + bl1).wl2 + bl2) (nkb=3)
// f16mask bit kb: srcKB is fp16
__global__ __launch_bounds__(256) void k_gemm_mfma(
    const void* __restrict__ src0, const void* __restrict__ src1,
    const void* __restrict__ src2, const short* __restrict__ wb,
    const float* __restrict__ dscale, const float* __restrict__ bias,
    const float* __restrict__ wl2, const float* __restrict__ bl2,
    void* __restrict__ Y, int n, int nkb, int mode, int f16mask) {
    __shared__ short wl[32768];          // 64 KB: [hi 16384][lo 16384]
    int tid = threadIdx.x;
    int wave = tid >> 6, lane = tid & 63;
    int g = lane >> 4, c = lane & 15;
    int base = blockIdx.x * 128 + wave * 32;

    f32x4 acc[2][8];
#pragma unroll
    for (int a = 0; a < 2; ++a)
#pragma unroll
        for (int b = 0; b < 8; ++b) acc[a][b] = (f32x4){0.f, 0.f, 0.f, 0.f};

    for (int kb = 0; kb < nkb; ++kb) {
        const void* src = (kb == 0) ? src0 : ((kb == 1) ? src1 : src2);
        int f16 = (f16mask >> kb) & 1;
        __syncthreads();
        {
            const int4* s = (const int4*)(wb + (size_t)kb * 32768);
            int4* d = (int4*)wl;
            for (int it = tid; it < 4096; it += 256) d[it] = s[it];
        }
        __syncthreads();
#pragma unroll
        for (int kk = 0; kk < 4; ++kk) {
            bf16x8 ah[2], al[2];
#pragma unroll
            for (int mf = 0; mf < 2; ++mf) {
                int node = base + mf * 16 + c;
                if (node >= n) node = n - 1;     // clamp; stores are guarded
                float v[8];
                loadA8(src, f16, (size_t)node, kk * 32 + g * 4, v);
                short2 s;
#pragma unroll
                for (int q = 0; q < 8; ++q) {
                    s = split_f(v[q]);
                    ah[mf][q] = s.x;
                    al[mf][q] = s.y;
                }
            }
#pragma unroll
            for (int nt = 0; nt < 8; ++nt) {
                int bidx = ((kk * 8 + nt) * 64 + lane) * 8;
                bf16x8 bh = *(const bf16x8*)&wl[bidx];
                bf16x8 bl = *(const bf16x8*)&wl[16384 + bidx];
#pragma unroll
                for (int mf = 0; mf < 2; ++mf) {
                    acc[mf][nt] = __builtin_amdgcn_mfma_f32_16x16x32_bf16(ah[mf], bh, acc[mf][nt], 0, 0, 0);
                    acc[mf][nt] = __builtin_amdgcn_mfma_f32_16x16x32_bf16(ah[mf], bl, acc[mf][nt], 0, 0, 0);
                    acc[mf][nt] = __builtin_amdgcn_mfma_f32_16x16x32_bf16(al[mf], bh, acc[mf][nt], 0, 0, 0);
                }
            }
        }
    }

    if (mode == 0) {
        __half* Yh = (__half*)Y;
#pragma unroll
        for (int mf = 0; mf < 2; ++mf) {
#pragma unroll
            for (int j = 0; j < 4; ++j) {
                int node = base + mf * 16 + g * 4 + j;   // row=(lane>>4)*4+reg
                if (node >= n) continue;
                float s = dscale[node];
#pragma unroll
                for (int nt = 0; nt < 8; ++nt)
                    Yh[(size_t)node * 128 + nt * 16 + c] =
                        __float2half(acc[mf][nt][j] * s);
            }
        }
    } else {
        float* Yf = (float*)Y;
        float wv[8], bv[8];
#pragma unroll
        for (int nt = 0; nt < 8; ++nt) {
            wv[nt] = wl2[nt * 16 + c];
            bv[nt] = bias[nt * 16 + c];
        }
        float blv = bl2[0];
#pragma unroll
        for (int mf = 0; mf < 2; ++mf) {
#pragma unroll
            for (int j = 0; j < 4; ++j) {
                float partial = 0.f;
#pragma unroll
                for (int nt = 0; nt < 8; ++nt)
                    partial += fmaxf(acc[mf][nt][j] + bv[nt], 0.f) * wv[nt];
#pragma unroll
                for (int m = 1; m < 16; m <<= 1) partial += __shfl_xor(partial, m);
                int node = base + mf * 16 + g * 4 + j;
                if (c == 0 && node < n)
                    Yf[node] = 1.f / (1.f + expf(-(partial + blv)));
            }
        }
    }
}

// ---------------- aggregation: half-row pass, 2 edges/wave-step ------------
// coff = 0 or 64. 32-lane group per edge (128B half-row); two groups per wave
// process edges e, e+1; shfl_xor(32) combine; lanes 0-31 store.
__global__ __launch_bounds__(256) void k_aggregate(
    const __half* __restrict__ xws, const float* __restrict__ dinv,
    const float* __restrict__ bias, const int* __restrict__ offs,
    const int* __restrict__ srow, __half* __restrict__ out, int n, int coff) {
    long long t = (long long)blockIdx.x * blockDim.x + threadIdx.x;
    int node = (int)(t >> 6);
    int l = (int)t & 63;
    if (node >= n) return;
    int sub = l >> 5, lc = l & 31;
    int start = offs[node], end = offs[node + 1];
    const __half* xb = xws + coff + lc * 2;   // lane's half2 within half-row
    float2 acc = make_float2(0.f, 0.f);
    int e = start + sub;
    for (; e + 14 < end; e += 16) {           // 8 edges per 32-lane group
        int r[8];
#pragma unroll
        for (int q = 0; q < 8; ++q)
            r[q] = __builtin_nontemporal_load(&srow[e + 2 * q]);
        float2 v[8];
#pragma unroll
        for (int q = 0; q < 8; ++q)
            v[q] = __half22float2(*(const __half2*)(xb + (size_t)r[q] * 128));
        float sx = 0.f, sy = 0.f;
#pragma unroll
        for (int q = 0; q < 8; ++q) { sx += v[q].x; sy += v[q].y; }
        acc.x += sx;
        acc.y += sy;
    }
    for (; e < end; e += 2) {
        float2 v = __half22float2(*(const __half2*)(xb + (size_t)srow[e] * 128));
        acc.x += v.x;
        acc.y += v.y;
    }
    acc.x += __shfl_xor(acc.x, 32);           // combine the two edge groups
    acc.y += __shfl_xor(acc.y, 32);
    if (sub == 0) {
        float2 self = __half22float2(*(const __half2*)(xb + (size_t)node * 128));
        acc.x += self.x;
        acc.y += self.y;
        float s = dinv[node];
        float2 b = *(const float2*)(bias + coff + lc * 2);
        acc.x = fmaxf(fmaf(acc.x, s, b.x), 0.f);
        acc.y = fmaxf(fmaf(acc.y, s, b.y), 0.f);
        __half2 hv = __float22half2_rn(acc);
        unsigned u;
        __builtin_memcpy(&u, &hv, 4);
        __builtin_nontemporal_store(u, (unsigned*)(out + (size_t)node * 128 + coff + lc * 2));
    }
}

extern "C" void kernel_launch(void* const* d_in, const int* in_sizes, int n_in,
                              void* d_out, int out_size, void* d_ws, size_t ws_size,
                              hipStream_t stream) {
    const float* x   = (const float*)d_in[0];
    const int*   ei  = (const int*)d_in[1];
    const float* W1  = (const float*)d_in[2];
    const float* b1  = (const float*)d_in[3];
    const float* W2  = (const float*)d_in[4];
    const float* b2  = (const float*)d_in[5];
    const float* Wl1 = (const float*)d_in[6];
    const float* bl1 = (const float*)d_in[7];
    const float* Wl2 = (const float*)d_in[8];
    const float* bl2 = (const float*)d_in[9];
    float* out = (float*)d_out;

    const int N = in_sizes[0] / 128;
    const int E = in_sizes[1] / 2;
    const int* row = ei;
    const int* col = ei + E;
    const int nbuk = (N + 63) >> 6;      // <= MAXBUK for N <= 131072

    char* ws = (char*)d_ws;
    size_t off = 0;
    auto alloc = [&](size_t bytes) {
        void* p = ws + off;
        off += (bytes + 255) & ~(size_t)255;
        return p;
    };
    float*  dinv     = (float*)alloc((size_t)N * 4);
    int*    partials = (int*)alloc((size_t)NB * nbuk * 4);
    int*    tot      = (int*)alloc((size_t)nbuk * 4);
    int*    base     = (int*)alloc((size_t)(nbuk + 1) * 4);
    int*    offs     = (int*)alloc((size_t)(N + 1) * 4);
    int*    bpack    = (int*)alloc((size_t)E * 4);
    int*    srow     = (int*)alloc((size_t)E * 4);
    short*  wb       = (short*)alloc((size_t)5 * 32768 * 2);
    __half* bufA     = (__half*)alloc((size_t)N * 128 * 2);  // xws (fp16)
    __half* bufB     = (__half*)alloc((size_t)N * 128 * 2);  // x1 (fp16)
    __half* bufC     = (__half*)alloc((size_t)N * 128 * 2);  // x2 (fp16)

    const int B = 256;
    int gG = (N + 127) / 128;                       // MFMA gemm tiles
    int gP = (5 * 16384 + B - 1) / B;
    int gS = (nbuk * 64 + B - 1) / B;               // k_bscan waves
    int gA = (int)(((long long)N * 64 + B - 1) / B);

    // ---- bucket CSR build + weight prep (no global random atomics) ----
    k_prep_w<<<gP, B, 0, stream>>>(W1, W2, Wl1, wb);
    k_bhist<<<NB, 1024, 0, stream>>>(col, partials, nbuk, E);
    k_bscan<<<gS, B, 0, stream>>>(partials, tot, nbuk);
    k_btot<<<1, B, 0, stream>>>(tot, base, nbuk, E);
    k_bscatter<<<NB, 1024, 0, stream>>>(row, col, base, partials, bpack, nbuk, E);
    k_bfill<<<nbuk, B, 0, stream>>>(bpack, base, offs, srow, dinv, N, E, nbuk);

    // ---- layer 1 ----
    k_gemm_mfma<<<gG, B, 0, stream>>>(x, nullptr, nullptr, wb,
                                      dinv, nullptr, nullptr, nullptr,
                                      bufA, N, 1, 0, 0);
    k_aggregate<<<gA, B, 0, stream>>>(bufA, dinv, b1, offs, srow, bufB, N, 0);
    k_aggregate<<<gA, B, 0, stream>>>(bufA, dinv, b1, offs, srow, bufB, N, 64);

    // ---- layer 2 ----
    k_gemm_mfma<<<gG, B, 0, stream>>>(bufB, nullptr, nullptr, wb + 32768,
                                      dinv, nullptr, nullptr, nullptr,
                                      bufA, N, 1, 0, 1);
    k_aggregate<<<gA, B, 0, stream>>>(bufA, dinv, b2, offs, srow, bufC, N, 0);
    k_aggregate<<<gA, B, 0, stream>>>(bufA, dinv, b2, offs, srow, bufC, N, 64);

    // ---- fused MLP head ----
    k_gemm_mfma<<<gG, B, 0, stream>>>(x, bufB, bufC, wb + 2 * 32768,
                                      nullptr, bl1, Wl2, bl2,
                                      out, N, 3, 1, 6);
}

// Round 12
// 429.596 us; speedup vs baseline: 1.3503x; 1.2750x over previous
//
#include <hip/hip_runtime.h>
#include <hip/hip_fp16.h>
#include <math.h>

// ---------------------------------------------------------------------------
// GCN: atomic-free bucket CSR build + wave-per-node fp16 gather aggregation
//      + split-bf16 MFMA GEMMs (fp32-accurate weights; fp16 activations).
//   bucket = col>>6 (64 nodes); LDS-privatized histogram + LDS cursors ->
//   zero global random atomics anywhere in the pipeline. NB=256 blocks.
//   xws = (X @ W) * dinv[node]  stored fp16; x1/x2 stored fp16 (exact
//   fp16->bf16 hi/lo split keeps GEMM math fp32-accurate).
//   x_out[n] = relu(dinv[n]*(xws[n] + sum_{e in CSR[n]} xws[srow[e]]) + b)
//   out = sigmoid(relu([x,x1,x2]@Wl1 + bl1) @ Wl2 + bl2)   (fused head)
// R11 lesson: half-row double-pass reduced traffic only 12% (reuse-dominated
// random gather) but doubled fixed cost -> single-pass is the floor.
// ---------------------------------------------------------------------------

typedef __attribute__((ext_vector_type(8))) short bf16x8;
typedef __attribute__((ext_vector_type(4))) float f32x4;

#define BSHIFT 6                 // 64 cols per bucket
#define NB 256                   // histogram / scatter blocks
#define MAXBUK 2048              // >= ceil(N/64); 8 KB LDS

// ---------------- bucket histogram (LDS-privatized) ----------------
__global__ __launch_bounds__(1024) void k_bhist(const int* __restrict__ col,
                                                int* __restrict__ partials,
                                                int nbuk, int e) {
    __shared__ int h[MAXBUK];
    int tid = threadIdx.x;
    for (int i = tid; i < nbuk; i += 1024) h[i] = 0;
    __syncthreads();
    for (long long i = (long long)blockIdx.x * 1024 + tid; i < e;
         i += (long long)NB * 1024)
        atomicAdd(&h[col[i] >> BSHIFT], 1);
    __syncthreads();
    for (int i = tid; i < nbuk; i += 1024)
        partials[(size_t)blockIdx.x * nbuk + i] = h[i];
}

// wave per bucket: exclusive-scan the NB block partials (4 chunks of 64)
__global__ __launch_bounds__(256) void k_bscan(int* __restrict__ partials,
                                               int* __restrict__ tot, int nbuk) {
    int gid = blockIdx.x * 256 + threadIdx.x;
    int w = gid >> 6, l = gid & 63;
    if (w >= nbuk) return;
    int carry = 0;
#pragma unroll
    for (int c = 0; c < NB / 64; ++c) {
        size_t idx = (size_t)(c * 64 + l) * nbuk + w;
        int v = partials[idx];
        int s = v;
        for (int d = 1; d < 64; d <<= 1) {
            int t = __shfl_up(s, d);
            if (l >= d) s += t;
        }
        partials[idx] = s - v + carry;   // exclusive within bucket
        carry += __shfl(s, 63);
    }
    if (l == 0) tot[w] = carry;
}

// single-block exclusive scan of bucket totals -> base
__global__ __launch_bounds__(256) void k_btot(const int* __restrict__ tot,
                                              int* __restrict__ base,
                                              int nbuk, int e) {
    __shared__ int s[256];
    __shared__ int carry_s;
    int t = threadIdx.x;
    if (t == 0) carry_s = 0;
    __syncthreads();
    for (int bb = 0; bb < nbuk; bb += 256) {
        int v = (bb + t < nbuk) ? tot[bb + t] : 0;
        s[t] = v;
        __syncthreads();
        for (int d = 1; d < 256; d <<= 1) {
            int a = (t >= d) ? s[t - d] : 0;
            __syncthreads();
            s[t] += a;
            __syncthreads();
        }
        int c0 = carry_s;
        if (bb + t < nbuk) base[bb + t] = s[t] - v + c0;
        __syncthreads();
        if (t == 0) carry_s = c0 + s[255];
        __syncthreads();
    }
    if (t == 0) base[nbuk] = e;
}

// scatter packed (row<<6 | col&63) with per-block LDS cursors
__global__ __launch_bounds__(1024) void k_bscatter(
    const int* __restrict__ row, const int* __restrict__ col,
    const int* __restrict__ base, const int* __restrict__ partials,
    int* __restrict__ bpack, int nbuk, int e) {
    __shared__ int cur[MAXBUK];
    int tid = threadIdx.x;
    for (int i = tid; i < nbuk; i += 1024)
        cur[i] = base[i] + partials[(size_t)blockIdx.x * nbuk + i];
    __syncthreads();
    for (long long i = (long long)blockIdx.x * 1024 + tid; i < e;
         i += (long long)NB * 1024) {
        int c = col[i];
        int pos = atomicAdd(&cur[c >> BSHIFT], 1);
        bpack[pos] = (row[i] << BSHIFT) | (c & 63);
    }
}

// per-bucket: node CSR (offs, srow) + dinv, all via LDS cursors (L2-local)
__global__ __launch_bounds__(256) void k_bfill(
    const int* __restrict__ bpack, const int* __restrict__ base,
    int* __restrict__ offs, int* __restrict__ srow,
    float* __restrict__ dinv, int n, int e, int nbuk) {
    __shared__ int h[64];
    __shared__ int cur[64];
    int b = blockIdx.x, tid = threadIdx.x;
    int nodeb = b << BSHIFT;
    if (tid < 64) h[tid] = 0;
    __syncthreads();
    int s0 = base[b], s1 = base[b + 1];
    for (int i = s0 + tid; i < s1; i += 256) atomicAdd(&h[bpack[i] & 63], 1);
    __syncthreads();
    if (tid < 64) {                      // threads 0-63 = wave 0
        int v = h[tid];
        int s = v;
        for (int d = 1; d < 64; d <<= 1) {
            int t = __shfl_up(s, d);
            if (tid >= d) s += t;
        }
        int myoff = s0 + s - v;          // exclusive scan + bucket base
        cur[tid] = myoff;
        int node = nodeb + tid;
        if (node < n) {
            offs[node] = myoff;
            dinv[node] = rsqrtf((float)v + 1.0f);
        }
    }
    if (b == nbuk - 1 && tid == 0) offs[n] = e;
    __syncthreads();
    for (int i = s0 + tid; i < s1; i += 256) {
        int p = bpack[i];
        int pos = atomicAdd(&cur[p & 63], 1);
        srow[pos] = p >> BSHIFT;
    }
}

// ---------------- weight prep: frag-ordered bf16 hi/lo ----------------
__global__ void k_prep_w(const float* __restrict__ W1, const float* __restrict__ W2,
                         const float* __restrict__ Wl1, short* __restrict__ wb) {
    int i = blockIdx.x * blockDim.x + threadIdx.x;
    if (i >= 5 * 16384) return;
    int blk = i >> 14, rem = i & 16383;
    int k = rem >> 7, n = rem & 127;
    float v;
    if (blk == 0) v = W1[rem];
    else if (blk == 1) v = W2[rem];
    else v = Wl1[((blk - 2) * 128 + k) * 128 + n];
    unsigned u = __float_as_uint(v);
    unsigned hb = u & 0xFFFF0000u;
    float lo = v - __uint_as_float(hb);
    unsigned lb = __float_as_uint(lo);
    int kk = k >> 5, km = k & 31;
    int half = km >> 4, kq = km & 15, g = kq >> 2, j = kq & 3;
    int nt = n >> 4, c = n & 15;
    size_t idx = ((size_t)(kk * 8 + nt) * 64 + (g * 16 + c)) * 8 + (half * 4 + j);
    size_t base = (size_t)blk * 32768;
    wb[base + idx] = (short)(hb >> 16);
    wb[base + 16384 + idx] = (short)(lb >> 16);
}

__device__ inline short2 split_f(float x) {
    unsigned u = __float_as_uint(x);
    unsigned hb = u & 0xFFFF0000u;
    short h = (short)(u >> 16);
    short l = (short)(__float_as_uint(x - __uint_as_float(hb)) >> 16);
    return make_short2(h, l);
}

// load 8 A-channels {off..off+3, off+16..off+19} as floats (fp32 or fp16 src)
__device__ inline void loadA8(const void* src, int f16, size_t node, int off,
                              float* v) {
    if (f16) {
        const __half* p = (const __half*)src + node * 128 + off;
        int2 a = *(const int2*)p;            // 4 halves
        int2 b = *(const int2*)(p + 16);     // 4 halves
        const __half2* ah = (const __half2*)&a;
        const __half2* bh = (const __half2*)&b;
        float2 f;
        f = __half22float2(ah[0]); v[0] = f.x; v[1] = f.y;
        f = __half22float2(ah[1]); v[2] = f.x; v[3] = f.y;
        f = __half22float2(bh[0]); v[4] = f.x; v[5] = f.y;
        f = __half22float2(bh[1]); v[6] = f.x; v[7] = f.y;
    } else {
        const float* p = (const float*)src + node * 128 + off;
        float4 v0 = *(const float4*)p;
        float4 v1 = *(const float4*)(p + 16);
        v[0] = v0.x; v[1] = v0.y; v[2] = v0.z; v[3] = v0.w;
        v[4] = v1.x; v[5] = v1.y; v[6] = v1.z; v[7] = v1.w;
    }
}

// ---------------- MFMA GEMM ----------------
// mode 0: Yh[node][ch] = fp16((src0 @ Wblk) * dscale[node])      (nkb=1)
// mode 1: out[node] = sigmoid(relu(sum_kb srcKB@Wblk + bl1).wl2 + bl2) (nkb=3)
// f16mask bit kb: srcKB is fp16
__global__ __launch_bounds__(256) void k_gemm_mfma(
    const void* __restrict__ src0, const void* __restrict__ src1,
    const void* __restrict__ src2, const short* __restrict__ wb,
    const float* __restrict__ dscale, const float* __restrict__ bias,
    const float* __restrict__ wl2, const float* __restrict__ bl2,
    void* __restrict__ Y, int n, int nkb, int mode, int f16mask) {
    __shared__ short wl[32768];          // 64 KB: [hi 16384][lo 16384]
    int tid = threadIdx.x;
    int wave = tid >> 6, lane = tid & 63;
    int g = lane >> 4, c = lane & 15;
    int base = blockIdx.x * 128 + wave * 32;

    f32x4 acc[2][8];
#pragma unroll
    for (int a = 0; a < 2; ++a)
#pragma unroll
        for (int b = 0; b < 8; ++b) acc[a][b] = (f32x4){0.f, 0.f, 0.f, 0.f};

    for (int kb = 0; kb < nkb; ++kb) {
        const void* src = (kb == 0) ? src0 : ((kb == 1) ? src1 : src2);
        int f16 = (f16mask >> kb) & 1;
        __syncthreads();
        {
            const int4* s = (const int4*)(wb + (size_t)kb * 32768);
            int4* d = (int4*)wl;
            for (int it = tid; it < 4096; it += 256) d[it] = s[it];
        }
        __syncthreads();
#pragma unroll
        for (int kk = 0; kk < 4; ++kk) {
            bf16x8 ah[2], al[2];
#pragma unroll
            for (int mf = 0; mf < 2; ++mf) {
                int node = base + mf * 16 + c;
                if (node >= n) node = n - 1;     // clamp; stores are guarded
                float v[8];
                loadA8(src, f16, (size_t)node, kk * 32 + g * 4, v);
                short2 s;
#pragma unroll
                for (int q = 0; q < 8; ++q) {
                    s = split_f(v[q]);
                    ah[mf][q] = s.x;
                    al[mf][q] = s.y;
                }
            }
#pragma unroll
            for (int nt = 0; nt < 8; ++nt) {
                int bidx = ((kk * 8 + nt) * 64 + lane) * 8;
                bf16x8 bh = *(const bf16x8*)&wl[bidx];
                bf16x8 bl = *(const bf16x8*)&wl[16384 + bidx];
#pragma unroll
                for (int mf = 0; mf < 2; ++mf) {
                    acc[mf][nt] = __builtin_amdgcn_mfma_f32_16x16x32_bf16(ah[mf], bh, acc[mf][nt], 0, 0, 0);
                    acc[mf][nt] = __builtin_amdgcn_mfma_f32_16x16x32_bf16(ah[mf], bl, acc[mf][nt], 0, 0, 0);
                    acc[mf][nt] = __builtin_amdgcn_mfma_f32_16x16x32_bf16(al[mf], bh, acc[mf][nt], 0, 0, 0);
                }
            }
        }
    }

    if (mode == 0) {
        __half* Yh = (__half*)Y;
#pragma unroll
        for (int mf = 0; mf < 2; ++mf) {
#pragma unroll
            for (int j = 0; j < 4; ++j) {
                int node = base + mf * 16 + g * 4 + j;   // row=(lane>>4)*4+reg
                if (node >= n) continue;
                float s = dscale[node];
#pragma unroll
                for (int nt = 0; nt < 8; ++nt)
                    Yh[(size_t)node * 128 + nt * 16 + c] =
                        __float2half(acc[mf][nt][j] * s);
            }
        }
    } else {
        float* Yf = (float*)Y;
        float wv[8], bv[8];
#pragma unroll
        for (int nt = 0; nt < 8; ++nt) {
            wv[nt] = wl2[nt * 16 + c];
            bv[nt] = bias[nt * 16 + c];
        }
        float blv = bl2[0];
#pragma unroll
        for (int mf = 0; mf < 2; ++mf) {
#pragma unroll
            for (int j = 0; j < 4; ++j) {
                float partial = 0.f;
#pragma unroll
                for (int nt = 0; nt < 8; ++nt)
                    partial += fmaxf(acc[mf][nt][j] + bv[nt], 0.f) * wv[nt];
#pragma unroll
                for (int m = 1; m < 16; m <<= 1) partial += __shfl_xor(partial, m);
                int node = base + mf * 16 + g * 4 + j;
                if (c == 0 && node < n)
                    Yf[node] = 1.f / (1.f + expf(-(partial + blv)));
            }
        }
    }
}

// ---------------- aggregation (wave-per-node fp16 gather, 16-deep) ---------
__global__ __launch_bounds__(256) void k_aggregate(
    const __half* __restrict__ xws, const float* __restrict__ dinv,
    const float* __restrict__ bias, const int* __restrict__ offs,
    const int* __restrict__ srow, __half* __restrict__ out, int n) {
    long long t = (long long)blockIdx.x * blockDim.x + threadIdx.x;
    int node = (int)(t >> 6);
    int l = (int)t & 63;
    if (node >= n) return;
    int start = offs[node], end = offs[node + 1];
    const __half* xb = xws + l * 2;      // lane's half2 within a row
    float2 acc = __half22float2(*(const __half2*)(xb + (size_t)node * 128));
    int e = start;
    for (; e + 15 < end; e += 16) {
        int r[16];
#pragma unroll
        for (int q = 0; q < 16; ++q)
            r[q] = __builtin_nontemporal_load(&srow[e + q]);
        float2 v[16];
#pragma unroll
        for (int q = 0; q < 16; ++q)
            v[q] = __half22float2(*(const __half2*)(xb + (size_t)r[q] * 128));
        float sx = 0.f, sy = 0.f;
#pragma unroll
        for (int q = 0; q < 16; ++q) { sx += v[q].x; sy += v[q].y; }
        acc.x += sx;
        acc.y += sy;
    }
    for (; e + 7 < end; e += 8) {
        int r[8];
#pragma unroll
        for (int q = 0; q < 8; ++q)
            r[q] = __builtin_nontemporal_load(&srow[e + q]);
        float2 v[8];
#pragma unroll
        for (int q = 0; q < 8; ++q)
            v[q] = __half22float2(*(const __half2*)(xb + (size_t)r[q] * 128));
        float sx = 0.f, sy = 0.f;
#pragma unroll
        for (int q = 0; q < 8; ++q) { sx += v[q].x; sy += v[q].y; }
        acc.x += sx;
        acc.y += sy;
    }
    for (; e < end; ++e) {
        float2 v = __half22float2(*(const __half2*)(xb + (size_t)srow[e] * 128));
        acc.x += v.x;
        acc.y += v.y;
    }
    float s = dinv[node];
    float2 b = *(const float2*)(bias + l * 2);
    acc.x = fmaxf(fmaf(acc.x, s, b.x), 0.f);
    acc.y = fmaxf(fmaf(acc.y, s, b.y), 0.f);
    __half2 hv = __float22half2_rn(acc);
    unsigned u;
    __builtin_memcpy(&u, &hv, 4);
    __builtin_nontemporal_store(u, (unsigned*)(out + (size_t)node * 128 + l * 2));
}

extern "C" void kernel_launch(void* const* d_in, const int* in_sizes, int n_in,
                              void* d_out, int out_size, void* d_ws, size_t ws_size,
                              hipStream_t stream) {
    const float* x   = (const float*)d_in[0];
    const int*   ei  = (const int*)d_in[1];
    const float* W1  = (const float*)d_in[2];
    const float* b1  = (const float*)d_in[3];
    const float* W2  = (const float*)d_in[4];
    const float* b2  = (const float*)d_in[5];
    const float* Wl1 = (const float*)d_in[6];
    const float* bl1 = (const float*)d_in[7];
    const float* Wl2 = (const float*)d_in[8];
    const float* bl2 = (const float*)d_in[9];
    float* out = (float*)d_out;

    const int N = in_sizes[0] / 128;
    const int E = in_sizes[1] / 2;
    const int* row = ei;
    const int* col = ei + E;
    const int nbuk = (N + 63) >> 6;      // <= MAXBUK for N <= 131072

    char* ws = (char*)d_ws;
    size_t off = 0;
    auto alloc = [&](size_t bytes) {
        void* p = ws + off;
        off += (bytes + 255) & ~(size_t)255;
        return p;
    };
    float*  dinv     = (float*)alloc((size_t)N * 4);
    int*    partials = (int*)alloc((size_t)NB * nbuk * 4);
    int*    tot      = (int*)alloc((size_t)nbuk * 4);
    int*    base     = (int*)alloc((size_t)(nbuk + 1) * 4);
    int*    offs     = (int*)alloc((size_t)(N + 1) * 4);
    int*    bpack    = (int*)alloc((size_t)E * 4);
    int*    srow     = (int*)alloc((size_t)E * 4);
    short*  wb       = (short*)alloc((size_t)5 * 32768 * 2);
    __half* bufA     = (__half*)alloc((size_t)N * 128 * 2);  // xws (fp16)
    __half* bufB     = (__half*)alloc((size_t)N * 128 * 2);  // x1 (fp16)
    __half* bufC     = (__half*)alloc((size_t)N * 128 * 2);  // x2 (fp16)

    const int B = 256;
    int gG = (N + 127) / 128;                       // MFMA gemm tiles
    int gP = (5 * 16384 + B - 1) / B;
    int gS = (nbuk * 64 + B - 1) / B;               // k_bscan waves
    int gA = (int)(((long long)N * 64 + B - 1) / B);

    // ---- bucket CSR build + weight prep (no global random atomics) ----
    k_prep_w<<<gP, B, 0, stream>>>(W1, W2, Wl1, wb);
    k_bhist<<<NB, 1024, 0, stream>>>(col, partials, nbuk, E);
    k_bscan<<<gS, B, 0, stream>>>(partials, tot, nbuk);
    k_btot<<<1, B, 0, stream>>>(tot, base, nbuk, E);
    k_bscatter<<<NB, 1024, 0, stream>>>(row, col, base, partials, bpack, nbuk, E);
    k_bfill<<<nbuk, B, 0, stream>>>(bpack, base, offs, srow, dinv, N, E, nbuk);

    // ---- layer 1 ----
    k_gemm_mfma<<<gG, B, 0, stream>>>(x, nullptr, nullptr, wb,
                                      dinv, nullptr, nullptr, nullptr,
                                      bufA, N, 1, 0, 0);
    k_aggregate<<<gA, B, 0, stream>>>(bufA, dinv, b1, offs, srow, bufB, N);

    // ---- layer 2 ----
    k_gemm_mfma<<<gG, B, 0, stream>>>(bufB, nullptr, nullptr, wb + 32768,
                                      dinv, nullptr, nullptr, nullptr,
                                      bufA, N, 1, 0, 1);
    k_aggregate<<<gA, B, 0, stream>>>(bufA, dinv, b2, offs, srow, bufC, N);

    // ---- fused MLP head ----
    k_gemm_mfma<<<gG, B, 0, stream>>>(x, bufB, bufC, wb + 2 * 32768,
                                      nullptr, bl1, Wl2, bl2,
                                      out, N, 3, 1, 6);
}